// Round 7
// baseline (193.066 us; speedup 1.0000x reference)
//
#include <hip/hip_runtime.h>
#include <math.h>

#define B_ 8192
#define D_ 4096
#define K_ 64
#define EPSF 1e-8f
#define LN2F 0.69314718056f
#define ENT_GRID 2048
#define SPLITS 16  // blocks per class per tensor

typedef float f32x4 __attribute__((ext_vector_type(4)));

// ---------------- kernels ----------------

// zero counts[64] + sd1[64] + sd8[64] (contiguous 192 words)
__global__ void k_init(int* __restrict__ z) {
  if (threadIdx.x < 192) z[threadIdx.x] = 0;
}

// one wave per row; K_ == 64 == wavefront: one coalesced read + ballot
__global__ void k_labels(const float* __restrict__ probs, int* __restrict__ labels,
                         int* __restrict__ counts, int* __restrict__ rowlist) {
  int row = blockIdx.x * 4 + (threadIdx.x >> 6);
  int lane = threadIdx.x & 63;
  float p = probs[(size_t)row * K_ + lane];
  unsigned long long m = __ballot(p > 0.5f);
  if (lane == 0) {
    int k = __ffsll(m) - 1;
    if (k >= 0) {
      labels[row] = k;
      int pos = atomicAdd(&counts[k], 1);
      rowlist[k * B_ + pos] = row;
    }
  }
}

// Single-pass norm + weighted class sum. BLOCK per (tensor, class, split):
// per row, each of the 4 waves reads a 1024-col quarter (4 f32x4/lane),
// partial ||a||^2 -> shfl-reduce -> LDS combine (parity buffered, one sync),
// then acc += w * quarter. Per-block partial C written to Cpart[split].
__global__ __launch_bounds__(256) void k_classnorm(
    const float* __restrict__ a1, const float* __restrict__ a8,
    const int* __restrict__ counts, const int* __restrict__ rowlist,
    float* __restrict__ Cpart1, float* __restrict__ Cpart8, float* __restrict__ sd1,
    float* __restrict__ sd8) {
  __shared__ float lred[2][4];
  int bid = blockIdx.x;
  const int NBLK = K_ * SPLITS;  // 1024 per tensor
  const float* a = (bid < NBLK) ? a1 : a8;
  float* Cpart = (bid < NBLK) ? Cpart1 : Cpart8;
  float* sd = (bid < NBLK) ? sd1 : sd8;
  bid = (bid < NBLK) ? bid : bid - NBLK;
  int k = bid & 63;
  int split = bid >> 6;  // 0..SPLITS-1
  int wave = threadIdx.x >> 6;
  int lane = threadIdx.x & 63;
  int cnt = counts[k];
  int beg = (cnt * split) / SPLITS;
  int end = (cnt * (split + 1)) / SPLITS;
  const int* rl = rowlist + k * B_;

  f32x4 acc0 = 0.f, acc1 = 0.f, acc2 = 0.f, acc3 = 0.f;
  int par = 0;
  for (int r = beg; r < end; ++r, par ^= 1) {
    int row = rl[r];
    // wave's quarter: f32x4 index = wave*256 + j*64 + lane
    const f32x4* rp = (const f32x4*)(a + (size_t)row * D_) + (wave * 256 + lane);
    f32x4 v0 = rp[0];
    f32x4 v1 = rp[64];
    f32x4 v2 = rp[128];
    f32x4 v3 = rp[192];
    float s = v0.x * v0.x + v0.y * v0.y + v0.z * v0.z + v0.w * v0.w;
    s += v1.x * v1.x + v1.y * v1.y + v1.z * v1.z + v1.w * v1.w;
    s += v2.x * v2.x + v2.y * v2.y + v2.z * v2.z + v2.w * v2.w;
    s += v3.x * v3.x + v3.y * v3.y + v3.z * v3.z + v3.w * v3.w;
#pragma unroll
    for (int o = 32; o > 0; o >>= 1) s += __shfl_xor(s, o);
    if (lane == 0) lred[par][wave] = s;
    __syncthreads();
    float stot = lred[par][0] + lred[par][1] + lred[par][2] + lred[par][3];
    float w = 1.0f / fmaxf(sqrtf(stot), EPSF);
    acc0 += w * v0;
    acc1 += w * v1;
    acc2 += w * v2;
    acc3 += w * v3;
    if (threadIdx.x == 0) atomicAdd(&sd[k], stot * w * w);  // rows in rl are class k
  }

  float* cp = Cpart + ((size_t)split * K_ + k) * D_ + wave * 1024;
  *(f32x4*)(cp + 4 * lane) = acc0;
  *(f32x4*)(cp + 4 * (64 + lane)) = acc1;
  *(f32x4*)(cp + 4 * (128 + lane)) = acc2;
  *(f32x4*)(cp + 4 * (192 + lane)) = acc3;
}

// mSm partials: 512 blocks; b<256 -> tensor1, else tensor8. k=b>>2, quarter q=b&3.
__global__ __launch_bounds__(256) void k_msm(const float* __restrict__ Cpart1,
                                             const float* __restrict__ Cpart8,
                                             float* __restrict__ msp1,
                                             float* __restrict__ msp8) {
  __shared__ float lds[4];
  int b = blockIdx.x;
  const float* Cpart = (b < 256) ? Cpart1 : Cpart8;
  float* msp = (b < 256) ? msp1 : msp8;
  b &= 255;
  int k = b >> 2;
  int q = b & 3;
  int t = threadIdx.x;
  int col = q * 1024 + 4 * t;
  f32x4 c = 0.f;
#pragma unroll
  for (int s = 0; s < SPLITS; ++s)
    c += *(const f32x4*)(Cpart + ((size_t)s * K_ + k) * D_ + col);
  float sq = c.x * c.x + c.y * c.y + c.z * c.z + c.w * c.w;
#pragma unroll
  for (int o = 32; o > 0; o >>= 1) sq += __shfl_down(sq, o);
  if ((t & 63) == 0) lds[t >> 6] = sq;
  __syncthreads();
  if (t == 0) msp[blockIdx.x & 255] = lds[0] + lds[1] + lds[2] + lds[3];
}

__device__ __forceinline__ float ent1(float p) {
  p = fminf(fmaxf(p, EPSF), 1.0f - EPSF);
  float q = 1.0f - p;
  float lp = __builtin_amdgcn_logf(p);  // v_log_f32: log2
  float lq = __builtin_amdgcn_logf(fmaxf(q, 1e-38f));
  return -(p * lp + q * lq);
}

__device__ __forceinline__ float ent4(f32x4 v) {
  return ent1(v.x) + ent1(v.y) + ent1(v.z) + ent1(v.w);
}

// binary entropy over both masks; plain loads, ILP-8, block-contiguous 64KB chunks
__global__ __launch_bounds__(256) void k_entropy(const f32x4* __restrict__ m1,
                                                 const f32x4* __restrict__ m8,
                                                 double* __restrict__ entpart) {
  __shared__ float lds[8];
  const int CHUNK = (B_ * D_ / 4) / ENT_GRID;  // 4096 f32x4 per block per mask
  int base = blockIdx.x * CHUNK;
  int t = threadIdx.x;
  float s1 = 0.f, s8 = 0.f;
#pragma unroll
  for (int o = 0; o < 4; ++o) {
    f32x4 a[4], b[4];
#pragma unroll
    for (int j = 0; j < 4; ++j) {
      int idx = base + t + (o * 4 + j) * 256;
      a[j] = m1[idx];
      b[j] = m8[idx];
    }
#pragma unroll
    for (int j = 0; j < 4; ++j) {
      s1 += ent4(a[j]);
      s8 += ent4(b[j]);
    }
  }
#pragma unroll
  for (int o = 32; o > 0; o >>= 1) {
    s1 += __shfl_down(s1, o);
    s8 += __shfl_down(s8, o);
  }
  int wid = t >> 6;
  if ((t & 63) == 0) { lds[wid] = s1; lds[4 + wid] = s8; }
  __syncthreads();
  if (t == 0) {
    float t1 = lds[0] + lds[1] + lds[2] + lds[3];
    float t8 = lds[4] + lds[5] + lds[6] + lds[7];
    entpart[blockIdx.x]            = (double)(t1 * LN2F);
    entpart[ENT_GRID + blockIdx.x] = (double)(t8 * LN2F);
  }
}

__global__ void k_final(const double* __restrict__ entpart, const int* __restrict__ counts,
                        const float* __restrict__ sd1, const float* __restrict__ sd8,
                        const float* __restrict__ msp1, const float* __restrict__ msp8,
                        float* __restrict__ out) {
  __shared__ double dl[8];
  int t = threadIdx.x;
  double e1 = 0.0, e8 = 0.0;
  for (int i = t; i < ENT_GRID; i += 256) {
    e1 += entpart[i];
    e8 += entpart[ENT_GRID + i];
  }
#pragma unroll
  for (int o = 32; o > 0; o >>= 1) {
    e1 += __shfl_down(e1, o);
    e8 += __shfl_down(e8, o);
  }
  int wid = t >> 6;
  if ((t & 63) == 0) { dl[wid] = e1; dl[4 + wid] = e8; }
  __syncthreads();
  float pcm1 = 0.f, pcm8 = 0.f, valid = 0.f;
  if (t < K_) {
    float mSm1 = msp1[t * 4] + msp1[t * 4 + 1] + msp1[t * 4 + 2] + msp1[t * 4 + 3];
    float mSm8 = msp8[t * 4] + msp8[t * 4 + 1] + msp8[t * 4 + 2] + msp8[t * 4 + 3];
    float n = (float)counts[t];
    bool v = (n >= 2.0f);
    float np = fmaxf(0.5f * n * (n - 1.0f), 1.0f);
    valid = v ? 1.0f : 0.f;
    pcm1 = v ? 0.5f * (mSm1 - sd1[t]) / np : 0.f;
    pcm8 = v ? 0.5f * (mSm8 - sd8[t]) / np : 0.f;
  }
#pragma unroll
  for (int o = 32; o > 0; o >>= 1) {
    pcm1 += __shfl_down(pcm1, o);
    pcm8 += __shfl_down(pcm8, o);
    valid += __shfl_down(valid, o);
  }
  if (t == 0) {
    double etot1 = dl[0] + dl[1] + dl[2] + dl[3];
    double etot8 = dl[4] + dl[5] + dl[6] + dl[7];
    float sp1 = (float)(etot1 / (double)((long long)B_ * D_));
    float sp8 = (float)(etot8 / (double)((long long)B_ * D_));
    float cs1 = (valid > 0.f) ? pcm1 / fmaxf(valid, 1.0f) : 0.f;
    float cs8 = (valid > 0.f) ? pcm8 / fmaxf(valid, 1.0f) : 0.f;
    float sim1 = -cs1, sim8 = -cs8;
    out[0] = sim1 + sim8 + 0.001f * (sp1 + sp8);
    out[1] = sim1;
    out[2] = sim8;
    out[3] = sp1;
    out[4] = sp8;
  }
}

// ---------------- launcher ----------------
// ws layout (bytes):
//   0        : double entpart[2][2048]      32768
//   32768    : int    labels[B]             32768
//   65536    : int    counts[64]            256  \
//   65792    : float  sd1[64]               256   } zeroed together (192 words)
//   66048    : float  sd8[64]               256  /
//   66304    : float  msp1[256]             1024
//   67328    : float  msp8[256]             1024
//   69632    : int    rowlist[K][B]         2097152
//   2166784  : float  Cpart1[16][K][D]      16777216
//   18944000 : float  Cpart8[16][K][D]      16777216
//   total ~35.7 MB (ws_size observed ~539 MB)

extern "C" void kernel_launch(void* const* d_in, const int* in_sizes, int n_in,
                              void* d_out, int out_size, void* d_ws, size_t ws_size,
                              hipStream_t stream) {
  const float* probs = (const float*)d_in[0];
  const float* a1 = (const float*)d_in[1];
  const float* a8 = (const float*)d_in[2];
  const float* m1 = (const float*)d_in[3];
  const float* m8 = (const float*)d_in[4];
  float* out = (float*)d_out;
  char* ws = (char*)d_ws;

  double* entpart = (double*)(ws + 0);
  int* labels = (int*)(ws + 32768);
  int* counts = (int*)(ws + 65536);
  float* sd1 = (float*)(ws + 65792);
  float* sd8 = (float*)(ws + 66048);
  float* msp1 = (float*)(ws + 66304);
  float* msp8 = (float*)(ws + 67328);
  int* rowlist = (int*)(ws + 69632);
  float* Cpart1 = (float*)(ws + 2166784);
  float* Cpart8 = (float*)(ws + 18944000);

  k_init<<<1, 256, 0, stream>>>(counts);
  k_labels<<<B_ / 4, 256, 0, stream>>>(probs, labels, counts, rowlist);
  // single pass over both acts tensors: norm + weighted class-sum, 2048 blocks
  k_classnorm<<<2 * K_ * SPLITS, 256, 0, stream>>>(a1, a8, counts, rowlist, Cpart1, Cpart8,
                                                   sd1, sd8);
  k_entropy<<<ENT_GRID, 256, 0, stream>>>((const f32x4*)m1, (const f32x4*)m8, entpart);
  k_msm<<<512, 256, 0, stream>>>(Cpart1, Cpart8, msp1, msp8);
  k_final<<<1, 256, 0, stream>>>(entpart, counts, sd1, sd8, msp1, msp8, out);
}

// Round 8
// 177.773 us; speedup vs baseline: 1.0860x; 1.0860x over previous
//
#include <hip/hip_runtime.h>
#include <math.h>

#define B_ 8192
#define D_ 4096
#define K_ 64
#define EPSF 1e-8f
#define LN2F 0.69314718056f
#define ENT_GRID 2048
#define SPLITS 16  // wave-level splits per class per tensor

typedef float f32x4 __attribute__((ext_vector_type(4)));

// ---------------- kernels ----------------

// zero counts[64] + sd1[64] + sd8[64] (contiguous 192 words)
__global__ void k_init(int* __restrict__ z) {
  if (threadIdx.x < 192) z[threadIdx.x] = 0;
}

// one wave per row; K_ == 64 == wavefront: one coalesced read + ballot
__global__ void k_labels(const float* __restrict__ probs, int* __restrict__ labels,
                         int* __restrict__ counts, int* __restrict__ rowlist) {
  int row = blockIdx.x * 4 + (threadIdx.x >> 6);
  int lane = threadIdx.x & 63;
  float p = probs[(size_t)row * K_ + lane];
  unsigned long long m = __ballot(p > 0.5f);
  if (lane == 0) {
    int k = __ffsll(m) - 1;
    if (k >= 0) {
      labels[row] = k;
      int pos = atomicAdd(&counts[k], 1);
      rowlist[k * B_ + pos] = row;
    }
  }
}

#define LOADROW(V, ROW)                                                        \
  {                                                                            \
    const f32x4* rp_ = (const f32x4*)(a + (size_t)(ROW)*D_) + lane;            \
    _Pragma("unroll") for (int j = 0; j < 16; ++j) V[j] = rp_[64 * j];         \
  }

#define CONSUME(V)                                                             \
  {                                                                            \
    float s_ = 0.f;                                                            \
    _Pragma("unroll") for (int j = 0; j < 16; ++j) s_ +=                       \
        V[j].x * V[j].x + V[j].y * V[j].y + V[j].z * V[j].z + V[j].w * V[j].w; \
    _Pragma("unroll") for (int o = 32; o > 0; o >>= 1) s_ += __shfl_xor(s_, o);\
    float w_ = 1.0f / fmaxf(sqrtf(s_), EPSF);                                  \
    _Pragma("unroll") for (int j = 0; j < 16; ++j) acc[j] += w_ * V[j];        \
    sdacc += s_ * w_ * w_;                                                     \
  }

// Single-pass norm + weighted class sum. One WAVE per row (no barrier, no
// in-loop atomics): 2-row pipelined 16-f32x4 loads, shfl_xor norm reduce,
// register accumulator; diag sum kept in a register, ONE atomic per wave.
// Grid: 512 blocks; bid<256 -> a1, else a8. bid&255: k=bid&63, split=(bid>>6)*4+wave.
__global__ __launch_bounds__(256) void k_classnorm(
    const float* __restrict__ a1, const float* __restrict__ a8,
    const int* __restrict__ counts, const int* __restrict__ rowlist,
    float* __restrict__ Cpart1, float* __restrict__ Cpart8, float* __restrict__ sd1,
    float* __restrict__ sd8) {
  int bid = blockIdx.x;
  const float* a = (bid < 256) ? a1 : a8;
  float* Cpart = (bid < 256) ? Cpart1 : Cpart8;
  float* sd = (bid < 256) ? sd1 : sd8;
  bid &= 255;
  int k = bid & 63;
  int wave = threadIdx.x >> 6;
  int lane = threadIdx.x & 63;
  int split = (bid >> 6) * 4 + wave;  // 0..15
  int cnt = counts[k];
  int beg = (cnt * split) / SPLITS;
  int end = (cnt * (split + 1)) / SPLITS;
  const int* rl = rowlist + k * B_;

  f32x4 acc[16];
#pragma unroll
  for (int j = 0; j < 16; ++j) acc[j] = 0.f;
  float sdacc = 0.f;

  f32x4 va[16], vb[16];
  int r = beg;
  int len = end - beg;
  if (len > 0) {
    LOADROW(va, rl[r]);
    int nPairs = len >> 1;
    for (int p = 0; p < nPairs; ++p, r += 2) {
      LOADROW(vb, rl[r + 1]);
      CONSUME(va);
      if (r + 2 < end) LOADROW(va, rl[r + 2]);
      CONSUME(vb);
    }
    if (r < end) CONSUME(va);  // odd tail
  }

  float* cp = Cpart + ((size_t)split * K_ + k) * D_;
#pragma unroll
  for (int j = 0; j < 16; ++j) *(f32x4*)(cp + 4 * (lane + 64 * j)) = acc[j];
  if (lane == 0) atomicAdd(&sd[k], sdacc);  // one atomic per wave, off hot path
}

// mSm partials: 512 blocks; b<256 -> tensor1, else tensor8. k=b>>2, quarter q=b&3.
__global__ __launch_bounds__(256) void k_msm(const float* __restrict__ Cpart1,
                                             const float* __restrict__ Cpart8,
                                             float* __restrict__ msp1,
                                             float* __restrict__ msp8) {
  __shared__ float lds[4];
  int b = blockIdx.x;
  const float* Cpart = (b < 256) ? Cpart1 : Cpart8;
  float* msp = (b < 256) ? msp1 : msp8;
  b &= 255;
  int k = b >> 2;
  int q = b & 3;
  int t = threadIdx.x;
  int col = q * 1024 + 4 * t;
  f32x4 c = 0.f;
#pragma unroll
  for (int s = 0; s < SPLITS; ++s)
    c += *(const f32x4*)(Cpart + ((size_t)s * K_ + k) * D_ + col);
  float sq = c.x * c.x + c.y * c.y + c.z * c.z + c.w * c.w;
#pragma unroll
  for (int o = 32; o > 0; o >>= 1) sq += __shfl_down(sq, o);
  if ((t & 63) == 0) lds[t >> 6] = sq;
  __syncthreads();
  if (t == 0) msp[blockIdx.x & 255] = lds[0] + lds[1] + lds[2] + lds[3];
}

__device__ __forceinline__ float ent1(float p) {
  p = fminf(fmaxf(p, EPSF), 1.0f - EPSF);
  float q = 1.0f - p;
  float lp = __builtin_amdgcn_logf(p);  // v_log_f32: log2
  float lq = __builtin_amdgcn_logf(fmaxf(q, 1e-38f));
  return -(p * lp + q * lq);
}

__device__ __forceinline__ float ent4(f32x4 v) {
  return ent1(v.x) + ent1(v.y) + ent1(v.z) + ent1(v.w);
}

// binary entropy over both masks; plain loads, 16 in flight, contiguous chunks
__global__ __launch_bounds__(256) void k_entropy(const f32x4* __restrict__ m1,
                                                 const f32x4* __restrict__ m8,
                                                 double* __restrict__ entpart) {
  __shared__ float lds[8];
  const int CHUNK = (B_ * D_ / 4) / ENT_GRID;  // 4096 f32x4 per block per mask
  int base = blockIdx.x * CHUNK;
  int t = threadIdx.x;
  float s1 = 0.f, s8 = 0.f;
#pragma unroll
  for (int o = 0; o < 2; ++o) {
    f32x4 a[8], b[8];
#pragma unroll
    for (int j = 0; j < 8; ++j) {
      int idx = base + t + (o * 8 + j) * 256;
      a[j] = m1[idx];
      b[j] = m8[idx];
    }
#pragma unroll
    for (int j = 0; j < 8; ++j) {
      s1 += ent4(a[j]);
      s8 += ent4(b[j]);
    }
  }
#pragma unroll
  for (int o = 32; o > 0; o >>= 1) {
    s1 += __shfl_down(s1, o);
    s8 += __shfl_down(s8, o);
  }
  int wid = t >> 6;
  if ((t & 63) == 0) { lds[wid] = s1; lds[4 + wid] = s8; }
  __syncthreads();
  if (t == 0) {
    float t1 = lds[0] + lds[1] + lds[2] + lds[3];
    float t8 = lds[4] + lds[5] + lds[6] + lds[7];
    entpart[blockIdx.x]            = (double)(t1 * LN2F);
    entpart[ENT_GRID + blockIdx.x] = (double)(t8 * LN2F);
  }
}

__global__ void k_final(const double* __restrict__ entpart, const int* __restrict__ counts,
                        const float* __restrict__ sd1, const float* __restrict__ sd8,
                        const float* __restrict__ msp1, const float* __restrict__ msp8,
                        float* __restrict__ out) {
  __shared__ double dl[8];
  int t = threadIdx.x;
  double e1 = 0.0, e8 = 0.0;
  for (int i = t; i < ENT_GRID; i += 256) {
    e1 += entpart[i];
    e8 += entpart[ENT_GRID + i];
  }
#pragma unroll
  for (int o = 32; o > 0; o >>= 1) {
    e1 += __shfl_down(e1, o);
    e8 += __shfl_down(e8, o);
  }
  int wid = t >> 6;
  if ((t & 63) == 0) { dl[wid] = e1; dl[4 + wid] = e8; }
  __syncthreads();
  float pcm1 = 0.f, pcm8 = 0.f, valid = 0.f;
  if (t < K_) {
    float mSm1 = msp1[t * 4] + msp1[t * 4 + 1] + msp1[t * 4 + 2] + msp1[t * 4 + 3];
    float mSm8 = msp8[t * 4] + msp8[t * 4 + 1] + msp8[t * 4 + 2] + msp8[t * 4 + 3];
    float n = (float)counts[t];
    bool v = (n >= 2.0f);
    float np = fmaxf(0.5f * n * (n - 1.0f), 1.0f);
    valid = v ? 1.0f : 0.f;
    pcm1 = v ? 0.5f * (mSm1 - sd1[t]) / np : 0.f;
    pcm8 = v ? 0.5f * (mSm8 - sd8[t]) / np : 0.f;
  }
#pragma unroll
  for (int o = 32; o > 0; o >>= 1) {
    pcm1 += __shfl_down(pcm1, o);
    pcm8 += __shfl_down(pcm8, o);
    valid += __shfl_down(valid, o);
  }
  if (t == 0) {
    double etot1 = dl[0] + dl[1] + dl[2] + dl[3];
    double etot8 = dl[4] + dl[5] + dl[6] + dl[7];
    float sp1 = (float)(etot1 / (double)((long long)B_ * D_));
    float sp8 = (float)(etot8 / (double)((long long)B_ * D_));
    float cs1 = (valid > 0.f) ? pcm1 / fmaxf(valid, 1.0f) : 0.f;
    float cs8 = (valid > 0.f) ? pcm8 / fmaxf(valid, 1.0f) : 0.f;
    float sim1 = -cs1, sim8 = -cs8;
    out[0] = sim1 + sim8 + 0.001f * (sp1 + sp8);
    out[1] = sim1;
    out[2] = sim8;
    out[3] = sp1;
    out[4] = sp8;
  }
}

// ---------------- launcher ----------------
// ws layout (bytes):
//   0        : double entpart[2][2048]      32768
//   32768    : int    labels[B]             32768
//   65536    : int    counts[64]            256  \
//   65792    : float  sd1[64]               256   } zeroed together (192 words)
//   66048    : float  sd8[64]               256  /
//   66304    : float  msp1[256]             1024
//   67328    : float  msp8[256]             1024
//   69632    : int    rowlist[K][B]         2097152
//   2166784  : float  Cpart1[16][K][D]      16777216
//   18944000 : float  Cpart8[16][K][D]      16777216
//   total ~35.7 MB (ws_size observed ~539 MB)

extern "C" void kernel_launch(void* const* d_in, const int* in_sizes, int n_in,
                              void* d_out, int out_size, void* d_ws, size_t ws_size,
                              hipStream_t stream) {
  const float* probs = (const float*)d_in[0];
  const float* a1 = (const float*)d_in[1];
  const float* a8 = (const float*)d_in[2];
  const float* m1 = (const float*)d_in[3];
  const float* m8 = (const float*)d_in[4];
  float* out = (float*)d_out;
  char* ws = (char*)d_ws;

  double* entpart = (double*)(ws + 0);
  int* labels = (int*)(ws + 32768);
  int* counts = (int*)(ws + 65536);
  float* sd1 = (float*)(ws + 65792);
  float* sd8 = (float*)(ws + 66048);
  float* msp1 = (float*)(ws + 66304);
  float* msp8 = (float*)(ws + 67328);
  int* rowlist = (int*)(ws + 69632);
  float* Cpart1 = (float*)(ws + 2166784);
  float* Cpart8 = (float*)(ws + 18944000);

  k_init<<<1, 256, 0, stream>>>(counts);
  k_labels<<<B_ / 4, 256, 0, stream>>>(probs, labels, counts, rowlist);
  // single pass over both acts tensors: norm + weighted class-sum fused per wave
  k_classnorm<<<512, 256, 0, stream>>>(a1, a8, counts, rowlist, Cpart1, Cpart8, sd1, sd8);
  k_entropy<<<ENT_GRID, 256, 0, stream>>>((const f32x4*)m1, (const f32x4*)m8, entpart);
  k_msm<<<512, 256, 0, stream>>>(Cpart1, Cpart8, msp1, msp8);
  k_final<<<1, 256, 0, stream>>>(entpart, counts, sd1, sd8, msp1, msp8, out);
}